// Round 2
// baseline (393.100 us; speedup 1.0000x reference)
//
#include <hip/hip_runtime.h>
#include <math.h>

#define NSN 4760
#define KNN 16
#define NT 6
#define NB 16

#ifndef __has_builtin
#define __has_builtin(x) 0
#endif

typedef _Float16 h2 __attribute__((ext_vector_type(2)));

__device__ __forceinline__ float fdot2f(h2 a, h2 b, float c) {
#if __has_builtin(__builtin_amdgcn_fdot2)
  return __builtin_amdgcn_fdot2(a, b, c, false);
#else
  return c + (float)a.x * (float)b.x + (float)a.y * (float)b.y;
#endif
}

// ---------------- Kernel A: per-sensor precompute (batch independent) ------
// S[n][h]      = query[n] @ W_nbr[2:,:] + b_nbr        (64)
// qlocal[n][h] = query[n] @ W_ql + b_ql                (64)
// qg[n][o]     = query[n] @ W_qg + b_qg                (128)
// c01[n]       = { W_nbr[0]·qlocal[n], W_nbr[1]·qlocal[n] }
__global__ void precompute_sensor(const float* __restrict__ pos_emb,
    const float* __restrict__ face_emb, const int* __restrict__ face_ids,
    const float* __restrict__ W_nbr, const float* __restrict__ b_nbr,
    const float* __restrict__ W_ql, const float* __restrict__ b_ql,
    const float* __restrict__ W_qg, const float* __restrict__ b_qg,
    float* __restrict__ S, float* __restrict__ qlocal,
    float* __restrict__ qg, float* __restrict__ c01)
{
  __shared__ __align__(16) float qL[4][128];
  const int w = threadIdx.x >> 6, lane = threadIdx.x & 63;
  const int gw = blockIdx.x * 4 + w;
  const int nw = gridDim.x * 4;
  for (int n = gw; n < NSN; n += nw) {
    const int fid = face_ids[n];
    const int e1 = lane + 64;
    const float q0 = pos_emb[n * 96 + lane];                 // lane < 96 always
    const float q1 = (e1 < 96) ? pos_emb[n * 96 + e1] : face_emb[fid * 32 + (e1 - 96)];
    qL[w][lane] = q0;
    qL[w][e1] = q1;
    float s  = b_nbr[lane], ql = b_ql[lane];
    float g0 = b_qg[lane],  g1 = b_qg[lane + 64];
    #pragma unroll 4
    for (int i = 0; i < 128; ++i) {
      const float qi = qL[w][i];
      s  += qi * W_nbr[(2 + i) * 64 + lane];
      ql += qi * W_ql[i * 64 + lane];
      g0 += qi * W_qg[i * 128 + lane];
      g1 += qi * W_qg[i * 128 + 64 + lane];
    }
    S[n * 64 + lane] = s;
    qlocal[n * 64 + lane] = ql;
    qg[n * 128 + lane] = g0;
    qg[n * 128 + 64 + lane] = g1;
    float p0 = W_nbr[lane] * ql, p1 = W_nbr[64 + lane] * ql;
    #pragma unroll
    for (int o = 32; o; o >>= 1) { p0 += __shfl_xor(p0, o); p1 += __shfl_xor(p1, o); }
    if (lane == 0) { c01[2 * n] = p0; c01[2 * n + 1] = p1; }
  }
}

// ---------------- Kernel B: latent -> K/V (96 rows) ------------------------
__global__ void precompute_latent(const float* __restrict__ latent,
    const float* __restrict__ face_emb,
    const float* __restrict__ W_lat, const float* __restrict__ b_lat,
    const float* __restrict__ W_lf, const float* __restrict__ b_lf,
    const float* __restrict__ W_k, const float* __restrict__ b_k,
    const float* __restrict__ W_v, const float* __restrict__ b_v,
    float* __restrict__ kg, float* __restrict__ vg)
{
  __shared__ __align__(16) float lat[1024];
  __shared__ __align__(16) float kv[128];
  const int bt = blockIdx.x;
  const int t = bt % NT;
  const int o = threadIdx.x;
  for (int i = o; i < 1024; i += 128) lat[i] = latent[bt * 1024 + i];
  __syncthreads();
  float acc = b_lat[o] + b_lf[o];
  #pragma unroll 8
  for (int i = 0; i < 1024; ++i) acc += lat[i] * W_lat[i * 128 + o];
  #pragma unroll
  for (int i = 0; i < 32; ++i) acc += face_emb[t * 32 + i] * W_lf[i * 128 + o];
  kv[o] = acc;
  __syncthreads();
  float kk = b_k[o], vv = b_v[o];
  #pragma unroll 4
  for (int i = 0; i < 128; ++i) {
    const float c = kv[i];
    kk += c * W_k[i * 128 + o];
    vv += c * W_v[i * 128 + o];
  }
  kg[bt * 128 + o] = kk;
  vg[bt * 128 + o] = vv;
}

// ---------------- Main fused kernel: one wave per (b,n) --------------------
__launch_bounds__(256, 2)
__global__ void fused_main(const float* __restrict__ x_flat,
    const int* __restrict__ mask, const int* __restrict__ knn,
    const float* __restrict__ Wnbr,
    const float* __restrict__ S, const float* __restrict__ qlocal,
    const float* __restrict__ qg, const float* __restrict__ c01,
    const float* __restrict__ kg, const float* __restrict__ vg,
    const float* __restrict__ Wgo, const float* __restrict__ bgo,
    const float* __restrict__ lng, const float* __restrict__ lnb,
    const float* __restrict__ Wm1, const float* __restrict__ bm1,
    const float* __restrict__ Wm2, const float* __restrict__ bm2,
    float* __restrict__ out)
{
  // f16 weight tiles, input-dim pairs packed for v_dot2
  __shared__ __align__(16) h2 WgS[64 * 128];   // [i2][o]  (W_go[2*i2][o], W_go[2*i2+1][o])
  __shared__ __align__(16) h2 WmS[96 * 64];    // [i2][o]  (W_m1[2*i2][o], W_m1[2*i2+1][o])
  __shared__ __align__(16) float qlS[4][64];
  __shared__ int   jjS[4][16];
  __shared__ float xxS[4][32];
  __shared__ float awS[4][16];
  __shared__ __align__(16) h2 gfS[4][64];
  __shared__ __align__(16) h2 cnS[4][96];

  const int tid = threadIdx.x;
  for (int idx = tid; idx < 64 * 128; idx += 256) {
    const int i2 = idx >> 7, o = idx & 127;
    h2 v = { (_Float16)Wgo[(2 * i2) * 128 + o], (_Float16)Wgo[(2 * i2 + 1) * 128 + o] };
    WgS[idx] = v;
  }
  for (int idx = tid; idx < 96 * 64; idx += 256) {
    const int i2 = idx >> 6, o = idx & 63;
    h2 v = { (_Float16)Wm1[(2 * i2) * 64 + o], (_Float16)Wm1[(2 * i2 + 1) * 64 + o] };
    WmS[idx] = v;
  }
  __syncthreads();

  const int w = tid >> 6, lane = tid & 63;
  // hoisted per-lane constants
  const float w0 = Wnbr[lane], w1 = Wnbr[64 + lane];
  const float bgo0 = bgo[2 * lane], bgo1 = bgo[2 * lane + 1];
  const float lng_a  = lng[lane],           lnb_a  = lnb[lane];
  const float lng_b0 = lng[64 + 2 * lane],  lnb_b0 = lnb[64 + 2 * lane];
  const float lng_b1 = lng[65 + 2 * lane],  lnb_b1 = lnb[65 + 2 * lane];
  const float bm1_l = bm1[lane], wm2_l = Wm2[lane], bm2_s = bm2[0];

  const int stride = gridDim.x * 4;
  for (int item = blockIdx.x * 4 + w; item < NB * NSN; item += stride) {
    const int b = item / NSN;
    const int n = item - b * NSN;

    // ---- stage per-item small vectors (wave-private LDS) ----
    const float ql = qlocal[n * 64 + lane];
    qlS[w][lane] = ql;
    if (lane < 16) {
      const int j = knn[n * 16 + lane];
      jjS[w][lane] = j;
      const float2 x01 = *(const float2*)(x_flat + (size_t)(b * NSN + j) * 2);
      xxS[w][lane] = x01.x;
      xxS[w][16 + lane] = x01.y;
    }

    // ---- Pass 1: KNN logits (4 lanes per neighbor k) ----
    const int k = lane >> 2, d = lane & 3;
    const int jk = jjS[w][k];
    const float4* Sr = (const float4*)(S + jk * 64 + d * 16);
    const float4* qr = (const float4*)(&qlS[w][d * 16]);
    float acc = 0.f;
    #pragma unroll
    for (int i = 0; i < 4; ++i) {
      const float4 sv = Sr[i]; const float4 qv = qr[i];
      acc += sv.x * qv.x + sv.y * qv.y + sv.z * qv.z + sv.w * qv.w;
    }
    acc += __shfl_xor(acc, 1); acc += __shfl_xor(acc, 2);
    const float c0 = c01[2 * n], c1 = c01[2 * n + 1];
    const float xk0 = xxS[w][k], xk1 = xxS[w][16 + k];
    float logit = (acc + xk0 * c0 + xk1 * c1) * 0.125f;
    if (mask[b * NSN + jk] != 0) logit = -10000.0f;
    float mx = logit;
    mx = fmaxf(mx, __shfl_xor(mx, 4));  mx = fmaxf(mx, __shfl_xor(mx, 8));
    mx = fmaxf(mx, __shfl_xor(mx, 16)); mx = fmaxf(mx, __shfl_xor(mx, 32));
    const float e = __expf(logit - mx);
    float s4 = e;
    s4 += __shfl_xor(s4, 4); s4 += __shfl_xor(s4, 8);
    s4 += __shfl_xor(s4, 16); s4 += __shfl_xor(s4, 32);     // = sum over the 16 k's (fixed d)
    const float attn = e / s4;
    if (d == 0) awS[w][k] = attn;
    float ax0 = attn * xk0, ax1 = attn * xk1;
    ax0 += __shfl_xor(ax0, 4); ax0 += __shfl_xor(ax0, 8);
    ax0 += __shfl_xor(ax0, 16); ax0 += __shfl_xor(ax0, 32);
    ax1 += __shfl_xor(ax1, 4); ax1 += __shfl_xor(ax1, 8);
    ax1 += __shfl_xor(ax1, 16); ax1 += __shfl_xor(ax1, 32);
    const float sx0 = ax0, sx1 = ax1;    // sum_k attn_k * x_k (each k once)

    // ---- Pass 2: local_feat[h] (lane = h), re-gather S rows (L1-hot) ----
    float lf = sx0 * w0 + sx1 * w1;
    #pragma unroll
    for (int kk = 0; kk < 16; ++kk) {
      lf += awS[w][kk] * S[jjS[w][kk] * 64 + lane];
    }

    // ---- Phase B: global attention (head h = lane>>4, dims 2l,2l+1) ----
    const float2 q2 = *(const float2*)(qg + n * 128 + 2 * lane);
    const float2* kgb = (const float2*)(kg + b * NT * 128);
    const float2* vgb = (const float2*)(vg + b * NT * 128);
    float gl[NT];
    #pragma unroll
    for (int t = 0; t < NT; ++t) {
      const float2 k2 = kgb[t * 64 + lane];
      float p = q2.x * k2.x + q2.y * k2.y;
      p += __shfl_xor(p, 1); p += __shfl_xor(p, 2);
      p += __shfl_xor(p, 4); p += __shfl_xor(p, 8);
      gl[t] = p * 0.17677669529663687f;   // 1/sqrt(32)
    }
    float gm = gl[0];
    #pragma unroll
    for (int t = 1; t < NT; ++t) gm = fmaxf(gm, gl[t]);
    float gs = 0.f;
    #pragma unroll
    for (int t = 0; t < NT; ++t) { gl[t] = __expf(gl[t] - gm); gs += gl[t]; }
    const float ginv = 1.0f / gs;
    float gfx = 0.f, gfy = 0.f;
    #pragma unroll
    for (int t = 0; t < NT; ++t) {
      const float2 v2 = vgb[t * 64 + lane];
      const float a = gl[t] * ginv;
      gfx += a * v2.x; gfy += a * v2.y;
    }
    { h2 v = { (_Float16)gfx, (_Float16)gfy }; gfS[w][lane] = v; }

    // ---- Phase C: g_out = g_feat @ W_go (+b), lane -> outputs 2l, 2l+1 ----
    float a0 = 0.f, a1 = 0.f;
    #pragma unroll 8
    for (int i2 = 0; i2 < 64; ++i2) {
      const h2 g2 = gfS[w][i2];                  // broadcast
      const h2 wa = WgS[i2 * 128 + 2 * lane];
      const h2 wb = WgS[i2 * 128 + 2 * lane + 1];
      a0 = fdot2f(g2, wa, a0);
      a1 = fdot2f(g2, wb, a1);
    }
    const float go0 = a0 + bgo0, go1 = a1 + bgo1;

    // ---- Phase D: LayerNorm over 192 (c[l], c[64+2l], c[65+2l]) ----
    float s1 = lf + go0 + go1;
    float s2 = lf * lf + go0 * go0 + go1 * go1;
    #pragma unroll
    for (int o = 32; o; o >>= 1) { s1 += __shfl_xor(s1, o); s2 += __shfl_xor(s2, o); }
    const float mu  = s1 * (1.0f / 192.0f);
    const float var = s2 * (1.0f / 192.0f) - mu * mu;
    const float rinv = rsqrtf(var + 1e-5f);
    const float n0 = (lf  - mu) * rinv * lng_a  + lnb_a;
    const float n1 = (go0 - mu) * rinv * lng_b0 + lnb_b0;
    const float n2 = (go1 - mu) * rinv * lng_b1 + lnb_b1;
    { h2 v = { (_Float16)n1, (_Float16)n2 }; cnS[w][32 + lane] = v; }
    const float n0o = __shfl_xor(n0, 1);
    if ((lane & 1) == 0) { h2 v = { (_Float16)n0, (_Float16)n0o }; cnS[w][lane >> 1] = v; }

    // ---- Phase E: MLP: normed @ W_m1 (+b), GELU(exact), @ W_m2 (+b) ----
    float m1a = bm1_l;
    #pragma unroll 8
    for (int i2 = 0; i2 < 96; ++i2) {
      m1a = fdot2f(cnS[w][i2], WmS[i2 * 64 + lane], m1a);
    }
    const float gelu = 0.5f * m1a * (1.0f + erff(m1a * 0.7071067811865476f));
    float pr = gelu * wm2_l;
    #pragma unroll
    for (int o = 32; o; o >>= 1) pr += __shfl_xor(pr, o);
    float res = pr + bm2_s;
    if (mask[item] == 0) res = 0.f;   // preds * (mask != 0)
    if (lane == 0) out[item] = res;
  }
}

extern "C" void kernel_launch(void* const* d_in, const int* in_sizes, int n_in,
                              void* d_out, int out_size, void* d_ws, size_t ws_size,
                              hipStream_t stream) {
  (void)in_sizes; (void)n_in; (void)out_size; (void)ws_size;
  const float* x_flat   = (const float*)d_in[0];
  const float* latent   = (const float*)d_in[1];
  const float* pos_emb  = (const float*)d_in[2];
  const float* face_emb = (const float*)d_in[3];
  const float* W_nbr = (const float*)d_in[4];
  const float* b_nbr = (const float*)d_in[5];
  const float* W_ql  = (const float*)d_in[6];
  const float* b_ql  = (const float*)d_in[7];
  const float* W_lat = (const float*)d_in[8];
  const float* b_lat = (const float*)d_in[9];
  const float* W_lf  = (const float*)d_in[10];
  const float* b_lf  = (const float*)d_in[11];
  const float* W_qg  = (const float*)d_in[12];
  const float* b_qg  = (const float*)d_in[13];
  const float* W_k   = (const float*)d_in[14];
  const float* b_k   = (const float*)d_in[15];
  const float* W_v   = (const float*)d_in[16];
  const float* b_v   = (const float*)d_in[17];
  const float* W_go  = (const float*)d_in[18];
  const float* b_go  = (const float*)d_in[19];
  const float* ln_g  = (const float*)d_in[20];
  const float* ln_b  = (const float*)d_in[21];
  const float* W_m1  = (const float*)d_in[22];
  const float* b_m1  = (const float*)d_in[23];
  const float* W_m2  = (const float*)d_in[24];
  const float* b_m2  = (const float*)d_in[25];
  const int* mask     = (const int*)d_in[26];
  const int* knn      = (const int*)d_in[27];
  const int* face_ids = (const int*)d_in[28];
  float* out = (float*)d_out;

  float* ws = (float*)d_ws;
  float* S      = ws;  ws += NSN * 64;
  float* qlocal = ws;  ws += NSN * 64;
  float* qgb    = ws;  ws += NSN * 128;
  float* c01    = ws;  ws += NSN * 2;
  float* kgb    = ws;  ws += NB * NT * 128;
  float* vgb    = ws;  ws += NB * NT * 128;

  precompute_sensor<<<1190, 256, 0, stream>>>(pos_emb, face_emb, face_ids,
      W_nbr, b_nbr, W_ql, b_ql, W_qg, b_qg, S, qlocal, qgb, c01);
  precompute_latent<<<96, 128, 0, stream>>>(latent, face_emb, W_lat, b_lat,
      W_lf, b_lf, W_k, b_k, W_v, b_v, kgb, vgb);
  fused_main<<<512, 256, 0, stream>>>(x_flat, mask, knn, W_nbr,
      S, qlocal, qgb, c01, kgb, vgb, W_go, b_go, ln_g, ln_b,
      W_m1, b_m1, W_m2, b_m2, out);
}